// Round 5
// baseline (1489.935 us; speedup 1.0000x reference)
//
#include <hip/hip_runtime.h>
#include <hip/hip_bf16.h>

// GCNConv forward: out = D^-1/2 (A+I) D^-1/2 (x W^T) + b
// N=100000, E=1600000, DIM=128. fp32 in/out, edge_index as int32.
//
// R10: three different sort pipelines all cost ~165us non-agg => the sort and
// flush machinery is latency-bound, not BW. So: (1) DELETE the counting sort -
// aggregate consumes the unsorted binned list via per-bin LDS fp32 accumulators
// (ds_add_f32, stride-65 bank spread); (2) scatter = one deposit pass into LDS
// bin buckets + ONE final contiguous flush (no per-round flushing), 512 blocks;
// (3) dinv = trivial per-bin histogram riding with the GEMM dispatch.
//   memset(cursors) -> [scatter || wconv] -> [dinvhist || gemm] -> bin_aggregate

#define DIM 128
#define BINSHIFT 8
#define BINSZ 256            // nodes per bin
#define NB 391               // ceil(100000/256)
#define CAPB 8192            // edges per bin capacity (mean 4096, sd ~64)
#define BUFCAP 28            // LDS slots per bin per block (mean 8, P(>28)~1e-9)
#define SBLK 512             // scatter blocks (full machine)
#define ACCSTRIDE 65         // floats per accum row: odd => bank spread
#define WSTRIDE 136          // shorts per LDS row in gemm epilogue buffer

typedef __attribute__((ext_vector_type(8))) short short8;
typedef __attribute__((ext_vector_type(4))) float f32x4;
typedef __attribute__((ext_vector_type(4))) unsigned short ushort4v;

__device__ inline unsigned short f2bf(float f) {
    unsigned u = __builtin_bit_cast(unsigned, f);
    return (unsigned short)((u + 0x7FFFu + ((u >> 16) & 1u)) >> 16);
}
__device__ inline float bflo(unsigned u) { return __builtin_bit_cast(float, u << 16); }
__device__ inline float bfhi(unsigned u) { return __builtin_bit_cast(float, u & 0xFFFF0000u); }

// ---- K1: bucket scatter (blocks 0..SBLK-1) || W->bf16 (last 2 blocks) ------
// Deposit packed (ldst<<17|src) into per-bin LDS buckets for the whole chunk,
// then ONE contiguous flush per (block,bin) with a single global cursor atomic.
__global__ __launch_bounds__(512) void scatter_ms(const int* __restrict__ ei, int E,
                                                  int* __restrict__ binCursor,
                                                  unsigned* __restrict__ binned,
                                                  const float* __restrict__ W,
                                                  unsigned short* __restrict__ wbf) {
    int t = threadIdx.x;
    if ((int)blockIdx.x >= SBLK) {
        // ---- wconv role: 2 blocks x 512 thr x 4 float4 = 16K floats
        int base = ((int)blockIdx.x - SBLK) * 2048 + t * 4;
#pragma unroll
        for (int i = 0; i < 4; ++i) {
            float4 w4 = ((const float4*)W)[base + i];
            ushort4v o; o.x = f2bf(w4.x); o.y = f2bf(w4.y); o.z = f2bf(w4.z); o.w = f2bf(w4.w);
            ((ushort4v*)wbf)[base + i] = o;
        }
        return;
    }

    __shared__ int cnt[NB];                 // 1.6 KB
    __shared__ unsigned sbuf[NB * BUFCAP];  // 43.8 KB
    for (int i = t; i < NB; i += 512) cnt[i] = 0;
    __syncthreads();

    int chunk = (E + SBLK - 1) / SBLK;      // 3125
    int base = blockIdx.x * chunk;
    int end = min(E, base + chunk);

    for (int i = base + t; i < end; i += 512) {
        int s = ei[i];
        int d = ei[E + i];
        int b = d >> BINSHIFT;
        unsigned p = ((unsigned)(d & (BINSZ - 1)) << 17) | (unsigned)s;
        int pos = atomicAdd(&cnt[b], 1);
        if (pos < BUFCAP) sbuf[b * BUFCAP + pos] = p;
        else binned[(size_t)b * CAPB + atomicAdd(&binCursor[b], 1)] = p;  // ~never
    }
    __syncthreads();
    // single flush: contiguous stores per bin, independent across threads
    for (int b = t; b < NB; b += 512) {
        int c = min(cnt[b], BUFCAP);
        if (c > 0) {
            int gb = atomicAdd(&binCursor[b], c);
            unsigned* gp = binned + (size_t)b * CAPB + gb;
            const unsigned* lp = &sbuf[b * BUFCAP];
            for (int j = 0; j < c; ++j) gp[j] = lp[j];
        }
    }
}

// ---- K2: dinv histogram (blocks 0..NB-1) || MFMA gemm (blocks NB..) --------
__global__ __launch_bounds__(512) void dinv_gemm(const unsigned* __restrict__ binned,
                                                 const int* __restrict__ binCursor,
                                                 float* __restrict__ dinv,
                                                 const float* __restrict__ x,
                                                 const unsigned short* __restrict__ wbf,
                                                 unsigned short* __restrict__ xlin, int N) {
    __shared__ __align__(16) char smem[8 * 16 * WSTRIDE * 2];   // 34.8 KB union
    int t = threadIdx.x;

    if ((int)blockIdx.x < NB) {
        // ---- dinv role: histogram local dst, no sort
        int* hist = (int*)smem;
        int b = blockIdx.x;
        int s0 = b * CAPB;
        int s1 = s0 + binCursor[b];
        if (t < BINSZ) hist[t] = 0;
        __syncthreads();
        for (int i = s0 + t; i < s1; i += 512)
            atomicAdd(&hist[binned[i] >> 17], 1);
        __syncthreads();
        int n = (b << BINSHIFT) + t;
        if (t < BINSZ && n < N)
            dinv[n] = rsqrtf((float)(hist[t] + 1));   // +1 self loop
        return;
    }

    // ---- GEMM role: 8 waves x 16 rows = 128 rows per block
    unsigned short* obuf = (unsigned short*)smem;
    int wid = t >> 6, lane = t & 63;
    int m = lane & 15, quad = lane >> 4;
    int row_base = ((int)blockIdx.x - NB) * 128 + wid * 16;

    f32x4 acc[8];
#pragma unroll
    for (int j = 0; j < 8; ++j) acc[j] = (f32x4){0.f, 0.f, 0.f, 0.f};

    int arow = row_base + m;
    if (arow >= N) arow = N - 1;
    const float* xr = x + (size_t)arow * DIM + quad * 8;

#pragma unroll
    for (int kc = 0; kc < 4; ++kc) {
        float4 a0 = *(const float4*)(xr + kc * 32);
        float4 a1 = *(const float4*)(xr + kc * 32 + 4);
        short8 af;
        af[0] = (short)f2bf(a0.x); af[1] = (short)f2bf(a0.y);
        af[2] = (short)f2bf(a0.z); af[3] = (short)f2bf(a0.w);
        af[4] = (short)f2bf(a1.x); af[5] = (short)f2bf(a1.y);
        af[6] = (short)f2bf(a1.z); af[7] = (short)f2bf(a1.w);
#pragma unroll
        for (int jt = 0; jt < 8; ++jt) {
            short8 bf = *(const short8*)&wbf[(jt * 16 + m) * DIM + kc * 32 + quad * 8];
            acc[jt] = __builtin_amdgcn_mfma_f32_16x16x32_bf16(af, bf, acc[jt], 0, 0, 0);
        }
    }

    // epilogue: C layout -> wave-local LDS -> row-major coalesced stores
    unsigned short* ob = &obuf[wid * 16 * WSTRIDE];
#pragma unroll
    for (int jt = 0; jt < 8; ++jt)
#pragma unroll
        for (int r = 0; r < 4; ++r)
            ob[(quad * 4 + r) * WSTRIDE + jt * 16 + m] = f2bf(acc[jt][r]);
    __syncthreads();
#pragma unroll
    for (int it = 0; it < 4; ++it) {
        int idx = it * 64 + lane;
        int r = idx >> 4;
        int cb = idx & 15;
        int grow = row_base + r;
        if (grow < N) {
            short8 v = *(const short8*)&ob[r * WSTRIDE + cb * 8];
            *(short8*)(xlin + (size_t)grow * DIM + cb * 8) = v;
        }
    }
}

// ---- K3: bin aggregate, NO sorted CSR: LDS fp32 accumulators per bin -------
// Grid = 2*NB: block (b,h) owns bin b, dim-half h (64 dims). 8 lanes per edge,
// 8 dims per lane; ds_add_f32 into lacc[256][65] (odd stride => bank spread).
__global__ __launch_bounds__(512) void bin_aggregate(const unsigned* __restrict__ binned,
                                                     const int* __restrict__ binCursor,
                                                     const unsigned short* __restrict__ xlin,
                                                     const float* __restrict__ dinv,
                                                     const float* __restrict__ bias,
                                                     float* __restrict__ out, int N) {
    __shared__ float lacc[BINSZ * ACCSTRIDE];   // 66.6 KB -> 2 blocks/CU
    int t = threadIdx.x;
    int b = blockIdx.x >> 1;
    int h = blockIdx.x & 1;
    int s0 = b * CAPB;
    int s1 = s0 + binCursor[b];

    for (int i = t; i < BINSZ * ACCSTRIDE; i += 512) lacc[i] = 0.f;
    __syncthreads();

    int g = t >> 3;          // edge slot 0..63
    int k = t & 7;           // dims k*8 .. k*8+7 of this half
    for (int i = s0 + g; i < s1; i += 64) {
        unsigned p = binned[i];
        int src = (int)(p & 0x1FFFFu);
        int ld = (int)(p >> 17);
        float dv = dinv[src];
        uint4 v = *(const uint4*)(xlin + (size_t)src * DIM + h * 64 + k * 8);
        float* ap = &lacc[ld * ACCSTRIDE + k * 8];
        atomicAdd(&ap[0], dv * bflo(v.x));
        atomicAdd(&ap[1], dv * bfhi(v.x));
        atomicAdd(&ap[2], dv * bflo(v.y));
        atomicAdd(&ap[3], dv * bfhi(v.y));
        atomicAdd(&ap[4], dv * bflo(v.z));
        atomicAdd(&ap[5], dv * bfhi(v.z));
        atomicAdd(&ap[6], dv * bflo(v.w));
        atomicAdd(&ap[7], dv * bfhi(v.w));
    }
    __syncthreads();

    // epilogue: 2 threads per node, 32 dims each; self-loop + scale + bias
    int nl = t >> 1;
    int n = (b << BINSHIFT) + nl;
    if (n < N) {
        int d0 = (t & 1) * 32;
        float di = dinv[n];
        const float* bp = bias + h * 64 + d0;
        float* op = out + (size_t)n * DIM + h * 64 + d0;
        const float* lp = &lacc[nl * ACCSTRIDE + d0];
#pragma unroll
        for (int j = 0; j < 32; j += 8) {
            uint4 v = *(const uint4*)(xlin + (size_t)n * DIM + h * 64 + d0 + j);
            float4 o1, o2;
            o1.x = di * (lp[j + 0] + di * bflo(v.x)) + bp[j + 0];
            o1.y = di * (lp[j + 1] + di * bfhi(v.x)) + bp[j + 1];
            o1.z = di * (lp[j + 2] + di * bflo(v.y)) + bp[j + 2];
            o1.w = di * (lp[j + 3] + di * bfhi(v.y)) + bp[j + 3];
            o2.x = di * (lp[j + 4] + di * bflo(v.z)) + bp[j + 4];
            o2.y = di * (lp[j + 5] + di * bfhi(v.z)) + bp[j + 5];
            o2.z = di * (lp[j + 6] + di * bflo(v.w)) + bp[j + 6];
            o2.w = di * (lp[j + 7] + di * bfhi(v.w)) + bp[j + 7];
            *(float4*)(op + j) = o1;
            *(float4*)(op + j + 4) = o2;
        }
    }
}

// ---- launch ----------------------------------------------------------------

extern "C" void kernel_launch(void* const* d_in, const int* in_sizes, int n_in,
                              void* d_out, int out_size, void* d_ws, size_t ws_size,
                              hipStream_t stream) {
    const float* x    = (const float*)d_in[0];
    const int*   ei   = (const int*)d_in[1];
    const float* W    = (const float*)d_in[2];
    const float* bias = (const float*)d_in[3];
    float* out = (float*)d_out;

    const int N = in_sizes[0] / DIM;      // 100000
    const int E = in_sizes[1] / 2;        // 1600000

    char* ws = (char*)d_ws;
    size_t off = 0;
    auto alloc = [&](size_t bytes) { size_t o = off; off = (off + bytes + 255) & ~(size_t)255; return o; };
    unsigned short* xlin = (unsigned short*)(ws + alloc((size_t)N * DIM * 2));   // 25.6 MB
    unsigned* binned = (unsigned*)(ws + alloc((size_t)NB * CAPB * 4));           // 12.8 MB
    float* dinv    = (float*)(ws + alloc((size_t)N * 4));
    int*  binCursor= (int*)  (ws + alloc((size_t)NB * 4 + 256));
    unsigned short* wbf = (unsigned short*)(ws + alloc((size_t)DIM * DIM * 2));  // 32 KB

    int GB = (N + 127) / 128;             // gemm blocks (782)

    hipMemsetAsync(binCursor, 0, (size_t)NB * 4, stream);
    scatter_ms<<<SBLK + 2, 512, 0, stream>>>(ei, E, binCursor, binned, W, wbf);
    dinv_gemm<<<NB + GB, 512, 0, stream>>>(binned, binCursor, dinv, x, wbf, xlin, N);
    bin_aggregate<<<2 * NB, 512, 0, stream>>>(binned, binCursor, xlin, dinv, bias, out, N);
}

// Round 6
// 235.513 us; speedup vs baseline: 6.3263x; 6.3263x over previous
//
#include <hip/hip_runtime.h>
#include <hip/hip_bf16.h>

// GCNConv forward: out = D^-1/2 (A+I) D^-1/2 (x W^T) + b
// N=100000, E=1600000, DIM=128. fp32 in/out, edge_index as int32.
//
// R11: R10's LDS-fp32-atomic aggregate falsified (1346us; LDS float atomics
// ~serial). Keep register-aggregate over sorted lists, but: (1) x->bf16
// pre-convert rides in scatter dispatch (GEMM A-frags become short8 loads);
// (2) counting sort FUSED into aggregate, entirely in LDS (global col/rowinfo
// deleted, ~20MB roundtrip gone); (3) dinv-hist rides with GEMM (R10-proven).
//   memset -> [scatter || wconv || xconv] -> [dinvhist || gemm] -> sort_agg

#define DIM 128
#define BINSHIFT 8
#define BINSZ 256            // nodes per bin
#define NB 391               // ceil(100000/256)
#define CAPB 8192            // edges per bin capacity (mean 4096, sd ~64)
#define BUFCAP 28            // LDS slots per bin per block (mean 8, P(>28)~1e-9)
#define SBLK 512             // scatter blocks (full machine)
#define XB 256               // x->bf16 convert blocks
#define HCAP 5120            // per half-bin LDS col capacity (mean 2048, +68sd)
#define WSTRIDE 136          // shorts per LDS row in gemm epilogue buffer

typedef __attribute__((ext_vector_type(8))) short short8;
typedef __attribute__((ext_vector_type(4))) float f32x4;
typedef __attribute__((ext_vector_type(4))) unsigned short ushort4v;

__device__ inline unsigned short f2bf(float f) {
    unsigned u = __builtin_bit_cast(unsigned, f);
    return (unsigned short)((u + 0x7FFFu + ((u >> 16) & 1u)) >> 16);
}
__device__ inline float bflo(unsigned u) { return __builtin_bit_cast(float, u << 16); }
__device__ inline float bfhi(unsigned u) { return __builtin_bit_cast(float, u & 0xFFFF0000u); }

// acc[j] += s * bf16_to_f32(v[j]) for 8 bf16 packed in a uint4
__device__ inline void bf8_axpy(uint4 v, float s, float* acc) {
    acc[0] = fmaf(s, bflo(v.x), acc[0]);
    acc[1] = fmaf(s, bfhi(v.x), acc[1]);
    acc[2] = fmaf(s, bflo(v.y), acc[2]);
    acc[3] = fmaf(s, bfhi(v.y), acc[3]);
    acc[4] = fmaf(s, bflo(v.z), acc[4]);
    acc[5] = fmaf(s, bfhi(v.z), acc[5]);
    acc[6] = fmaf(s, bflo(v.w), acc[6]);
    acc[7] = fmaf(s, bfhi(v.w), acc[7]);
}

// ---- K1: bucket scatter (0..SBLK-1) || wconv (2) || xconv (XB) -------------
__global__ __launch_bounds__(512) void scatter_ms(const int* __restrict__ ei, int E,
                                                  int* __restrict__ binCursor,
                                                  unsigned* __restrict__ binned,
                                                  const float* __restrict__ W,
                                                  unsigned short* __restrict__ wbf,
                                                  const float* __restrict__ x,
                                                  unsigned short* __restrict__ xbf, int N) {
    int t = threadIdx.x;
    int bx = blockIdx.x;
    if (bx >= SBLK + 2) {
        // ---- xconv role: x (fp32) -> xbf (bf16), short8 chunks
        int nchunk = N * DIM / 8;                 // 1.6M
        for (int c = (bx - SBLK - 2) * 512 + t; c < nchunk; c += XB * 512) {
            const float4* xp = (const float4*)x + (size_t)c * 2;
            float4 a = xp[0], b = xp[1];
            short8 o;
            o[0] = (short)f2bf(a.x); o[1] = (short)f2bf(a.y);
            o[2] = (short)f2bf(a.z); o[3] = (short)f2bf(a.w);
            o[4] = (short)f2bf(b.x); o[5] = (short)f2bf(b.y);
            o[6] = (short)f2bf(b.z); o[7] = (short)f2bf(b.w);
            ((short8*)xbf)[c] = o;
        }
        return;
    }
    if (bx >= SBLK) {
        // ---- wconv role: 2 blocks x 512 thr x 4 float4 = 16K floats
        int base = (bx - SBLK) * 2048 + t * 4;
#pragma unroll
        for (int i = 0; i < 4; ++i) {
            float4 w4 = ((const float4*)W)[base + i];
            ushort4v o; o.x = f2bf(w4.x); o.y = f2bf(w4.y); o.z = f2bf(w4.z); o.w = f2bf(w4.w);
            ((ushort4v*)wbf)[base + i] = o;
        }
        return;
    }

    __shared__ int cnt[NB];                 // 1.6 KB
    __shared__ unsigned sbuf[NB * BUFCAP];  // 43.8 KB
    for (int i = t; i < NB; i += 512) cnt[i] = 0;
    __syncthreads();

    int chunk = (E + SBLK - 1) / SBLK;      // 3125
    int base = bx * chunk;
    int end = min(E, base + chunk);

    for (int i = base + t; i < end; i += 512) {
        int s = ei[i];
        int d = ei[E + i];
        int b = d >> BINSHIFT;
        unsigned p = ((unsigned)(d & (BINSZ - 1)) << 17) | (unsigned)s;
        int pos = atomicAdd(&cnt[b], 1);
        if (pos < BUFCAP) sbuf[b * BUFCAP + pos] = p;
        else binned[(size_t)b * CAPB + atomicAdd(&binCursor[b], 1)] = p;  // ~never
    }
    __syncthreads();
    // single flush: contiguous stores per bin, independent across threads
    for (int b = t; b < NB; b += 512) {
        int c = min(cnt[b], BUFCAP);
        if (c > 0) {
            int gb = atomicAdd(&binCursor[b], c);
            unsigned* gp = binned + (size_t)b * CAPB + gb;
            const unsigned* lp = &sbuf[b * BUFCAP];
            for (int j = 0; j < c; ++j) gp[j] = lp[j];
        }
    }
}

// ---- K2: dinv histogram (blocks 0..NB-1) || MFMA gemm (blocks NB..) --------
__global__ __launch_bounds__(512) void dinv_gemm(const unsigned* __restrict__ binned,
                                                 const int* __restrict__ binCursor,
                                                 float* __restrict__ dinv,
                                                 const unsigned short* __restrict__ xbf,
                                                 const unsigned short* __restrict__ wbf,
                                                 unsigned short* __restrict__ xlin, int N) {
    __shared__ __align__(16) char smem[8 * 16 * WSTRIDE * 2];   // 34.8 KB union
    int t = threadIdx.x;

    if ((int)blockIdx.x < NB) {
        // ---- dinv role: histogram local dst, no sort
        int* hist = (int*)smem;
        int b = blockIdx.x;
        int s0 = b * CAPB;
        int s1 = s0 + binCursor[b];
        if (t < BINSZ) hist[t] = 0;
        __syncthreads();
        for (int i = s0 + t; i < s1; i += 512)
            atomicAdd(&hist[binned[i] >> 17], 1);
        __syncthreads();
        int n = (b << BINSHIFT) + t;
        if (t < BINSZ && n < N)
            dinv[n] = rsqrtf((float)(hist[t] + 1));   // +1 self loop
        return;
    }

    // ---- GEMM role: 8 waves x 16 rows = 128 rows per block; A from bf16 xbf
    unsigned short* obuf = (unsigned short*)smem;
    int wid = t >> 6, lane = t & 63;
    int m = lane & 15, quad = lane >> 4;
    int row_base = ((int)blockIdx.x - NB) * 128 + wid * 16;

    f32x4 acc[8];
#pragma unroll
    for (int j = 0; j < 8; ++j) acc[j] = (f32x4){0.f, 0.f, 0.f, 0.f};

    int arow = row_base + m;
    if (arow >= N) arow = N - 1;
    const unsigned short* xr = xbf + (size_t)arow * DIM + quad * 8;

#pragma unroll
    for (int kc = 0; kc < 4; ++kc) {
        short8 af = *(const short8*)(xr + kc * 32);
#pragma unroll
        for (int jt = 0; jt < 8; ++jt) {
            short8 bf = *(const short8*)&wbf[(jt * 16 + m) * DIM + kc * 32 + quad * 8];
            acc[jt] = __builtin_amdgcn_mfma_f32_16x16x32_bf16(af, bf, acc[jt], 0, 0, 0);
        }
    }

    // epilogue: C layout -> wave-local LDS -> row-major coalesced stores
    unsigned short* ob = &obuf[wid * 16 * WSTRIDE];
#pragma unroll
    for (int jt = 0; jt < 8; ++jt)
#pragma unroll
        for (int r = 0; r < 4; ++r)
            ob[(quad * 4 + r) * WSTRIDE + jt * 16 + m] = f2bf(acc[jt][r]);
    __syncthreads();
#pragma unroll
    for (int it = 0; it < 4; ++it) {
        int idx = it * 64 + lane;
        int r = idx >> 4;
        int cb = idx & 15;
        int grow = row_base + r;
        if (grow < N) {
            short8 v = *(const short8*)&ob[r * WSTRIDE + cb * 8];
            *(short8*)(xlin + (size_t)grow * DIM + cb * 8) = v;
        }
    }
}

// ---- K3: fused in-LDS counting sort + register aggregate -------------------
// Block (b,h): sorts its half-bin's edges (local dst 128*h..128*h+127) into a
// 20KB LDS col, then aggregates 128 nodes with 16 lanes/node (chunks of 4).
__global__ __launch_bounds__(512) void sort_aggregate(const unsigned* __restrict__ binned,
                                                      const int* __restrict__ binCursor,
                                                      const unsigned short* __restrict__ xlin,
                                                      const float* __restrict__ dinv,
                                                      const float* __restrict__ bias,
                                                      float* __restrict__ out, int N) {
    __shared__ int lcol[HCAP];                        // 20 KB
    __shared__ int hist[128], cur[128], sA[128], sB[128];
    int t = threadIdx.x;
    int b = blockIdx.x >> 1;
    int h = blockIdx.x & 1;
    int s0 = b * CAPB;
    int s1 = s0 + binCursor[b];

    if (t < 128) { hist[t] = 0; cur[t] = 0; }
    __syncthreads();
    // pass 1: histogram my half's local dst
    for (int i = s0 + t; i < s1; i += 512) {
        unsigned p = binned[i];
        int ld = p >> 17;
        if ((ld >> 7) == h) atomicAdd(&hist[ld & 127], 1);
    }
    __syncthreads();
    // Hillis-Steele inclusive scan over 128 (7 steps, ping-pong sA/sB)
    if (t < 128) sA[t] = hist[t];
    __syncthreads();
    int* sp = sA; int* dp = sB;
    for (int step = 1; step < 128; step <<= 1) {
        if (t < 128) {
            int v = sp[t];
            if (t >= step) v += sp[t - step];
            dp[t] = v;
        }
        __syncthreads();
        int* tmp = sp; sp = dp; dp = tmp;
    }
    // sp = inclusive scan; exclusive base -> dp
    if (t < 128) dp[t] = sp[t] - hist[t];
    __syncthreads();
    // pass 2: place src ids grouped by local node
    for (int i = s0 + t; i < s1; i += 512) {
        unsigned p = binned[i];
        int ld = p >> 17;
        if ((ld >> 7) == h) {
            int li = ld & 127;
            int pos = dp[li] + atomicAdd(&cur[li], 1);
            if (pos < HCAP) lcol[pos] = (int)(p & 0x1FFFFu);
        }
    }
    __syncthreads();

    // aggregate: 4 rounds x 32 nodes (16 lanes/node, 8 dims/lane)
    const uint4* xl = (const uint4*)xlin;
    int lane = t & 15;
#pragma unroll
    for (int round = 0; round < 4; ++round) {
        int l = round * 32 + (t >> 4);
        int n = (b << BINSHIFT) + (h << 7) + l;
        if (n >= N) continue;
        int r0 = dp[l], r1 = r0 + hist[l];
        float di = rsqrtf((float)(hist[l] + 1));

        float acc[8] = {};
        bf8_axpy(xl[(size_t)n * 16 + lane], di, acc);   // self loop

        for (int i = r0; i < r1; i += 4) {
            int rem = r1 - i;
            int e0 = lcol[i];
            int e1 = lcol[rem > 1 ? i + 1 : i];
            int e2 = lcol[rem > 2 ? i + 2 : i];
            int e3 = lcol[rem > 3 ? i + 3 : i];
            float d0 = dinv[e0];
            float d1 = rem > 1 ? dinv[e1] : 0.f;
            float d2 = rem > 2 ? dinv[e2] : 0.f;
            float d3 = rem > 3 ? dinv[e3] : 0.f;
            uint4 v0 = xl[(size_t)e0 * 16 + lane];
            uint4 v1 = xl[(size_t)e1 * 16 + lane];
            uint4 v2 = xl[(size_t)e2 * 16 + lane];
            uint4 v3 = xl[(size_t)e3 * 16 + lane];
            bf8_axpy(v0, d0, acc);
            bf8_axpy(v1, d1, acc);
            bf8_axpy(v2, d2, acc);
            bf8_axpy(v3, d3, acc);
        }

        const float4* b4 = (const float4*)(bias + lane * 8);
        float4 bl = b4[0], bh = b4[1];
        float4 olo = make_float4(di * acc[0] + bl.x, di * acc[1] + bl.y,
                                 di * acc[2] + bl.z, di * acc[3] + bl.w);
        float4 ohi = make_float4(di * acc[4] + bh.x, di * acc[5] + bh.y,
                                 di * acc[6] + bh.z, di * acc[7] + bh.w);
        float4* op = (float4*)(out + (size_t)n * DIM + lane * 8);
        op[0] = olo;
        op[1] = ohi;
    }
}

// ---- launch ----------------------------------------------------------------

extern "C" void kernel_launch(void* const* d_in, const int* in_sizes, int n_in,
                              void* d_out, int out_size, void* d_ws, size_t ws_size,
                              hipStream_t stream) {
    const float* x    = (const float*)d_in[0];
    const int*   ei   = (const int*)d_in[1];
    const float* W    = (const float*)d_in[2];
    const float* bias = (const float*)d_in[3];
    float* out = (float*)d_out;

    const int N = in_sizes[0] / DIM;      // 100000
    const int E = in_sizes[1] / 2;        // 1600000

    char* ws = (char*)d_ws;
    size_t off = 0;
    auto alloc = [&](size_t bytes) { size_t o = off; off = (off + bytes + 255) & ~(size_t)255; return o; };
    unsigned short* xlin = (unsigned short*)(ws + alloc((size_t)N * DIM * 2));   // 25.6 MB
    unsigned short* xbf  = (unsigned short*)(ws + alloc((size_t)N * DIM * 2));   // 25.6 MB
    unsigned* binned = (unsigned*)(ws + alloc((size_t)NB * CAPB * 4));           // 12.8 MB
    float* dinv    = (float*)(ws + alloc((size_t)N * 4));
    int*  binCursor= (int*)  (ws + alloc((size_t)NB * 4 + 256));
    unsigned short* wbf = (unsigned short*)(ws + alloc((size_t)DIM * DIM * 2));  // 32 KB

    int GB = (N + 127) / 128;             // gemm blocks (782)

    hipMemsetAsync(binCursor, 0, (size_t)NB * 4, stream);
    scatter_ms<<<SBLK + 2 + XB, 512, 0, stream>>>(ei, E, binCursor, binned, W, wbf, x, xbf, N);
    dinv_gemm<<<NB + GB, 512, 0, stream>>>(binned, binCursor, dinv, xbf, wbf, xlin, N);
    sort_aggregate<<<2 * NB, 512, 0, stream>>>(binned, binCursor, xlin, dinv, bias, out, N);
}